// Round 3
// baseline (73.161 us; speedup 1.0000x reference)
//
#include <hip/hip_runtime.h>

#define KN      1024
#define FAN_IN  16
#define NSP     64
#define THRESH  12

__device__ __forceinline__ float tanh_fast(float x) {
    float ax = fabsf(x);
    float e  = __expf(-2.0f * ax);                       // e^{-2|x|}, native v_exp
    float r  = 1.0f - 2.0f * e * __builtin_amdgcn_rcpf(1.0f + e);
    return copysignf(r, x);
}

// 1 block = 1 node. 256 threads; thread owns a 4x4 output tile:
// rows r0..r0+3 (r0 = (tid>>4)*4), cols c0..c0+3 (c0 = (tid&15)*4).
// Per channel: stream 6 input rows of 6 values (float4 + 2 masked halo scalars),
// FMA each row into the affected accumulators immediately (row then dead).
__global__ __launch_bounds__(256) void decoder_kernel(
    const float* __restrict__ prev_outputs,      // [1024,64,64]
    const void*  __restrict__ prev_is_active,    // [1024] bool(1B) or int32 (sniffed)
    const int*   __restrict__ parent_indices,    // [1024,16]
    const float* __restrict__ Wt,                // [1024,16,3,3]
    const float* __restrict__ bias,              // [1024]
    float*       __restrict__ out)               // [1024*4096] + [1024] activity
{
    const int k   = blockIdx.x;
    const int tid = threadIdx.x;
    const int cg  = tid & 15;
    const int rg  = tid >> 4;
    const int c0  = cg * 4;
    const int r0  = rg * 4;

    // --- sniff flag encoding: numpy bool (1 byte) vs int32. Deterministic. ---
    bool bytemode = false;
    {
        const unsigned* sv = (const unsigned*)prev_is_active;
        #pragma unroll
        for (int i = 0; i < 16; ++i)
            if (sv[i] > 1u) bytemode = true;
    }

    // --- activity gate: uniform scalar work ---
    int cnt = 0;
    #pragma unroll
    for (int i = 0; i < FAN_IN; ++i) {
        int p = parent_indices[k * FAN_IN + i];
        int f;
        if (bytemode) f = (((const unsigned char*)prev_is_active)[p] != 0);
        else          f = (((const int*)prev_is_active)[p] != 0);
        cnt += f;
    }
    const bool active = (cnt >= THRESH);

    const size_t obase = (size_t)k * (NSP * NSP);
    if (tid == 0)
        out[(size_t)KN * NSP * NSP + k] = active ? 1.0f : 0.0f;

    if (!active) {
        float4 z = make_float4(0.f, 0.f, 0.f, 0.f);
        float4* o4 = (float4*)(out + obase);
        #pragma unroll
        for (int i = tid; i < NSP * NSP / 4; i += 256) o4[i] = z;
        return;
    }

    // halo masks (0/1 floats) + clamped halo column offsets, hoisted
    const float mL = (cg > 0)  ? 1.0f : 0.0f;
    const float mR = (cg < 15) ? 1.0f : 0.0f;
    const float mT = (rg > 0)  ? 1.0f : 0.0f;
    const float mB = (rg < 15) ? 1.0f : 0.0f;
    const int   cL = (cg > 0)  ? c0 - 1 : 0;     // clamped, in-bounds
    const int   cR = (cg < 15) ? c0 + 4 : 63;    // clamped, in-bounds

    float acc[4][4];
    #pragma unroll
    for (int r = 0; r < 4; ++r)
        #pragma unroll
        for (int c = 0; c < 4; ++c) acc[r][c] = 0.0f;

    for (int ch = 0; ch < FAN_IN; ++ch) {
        const int p = parent_indices[k * FAN_IN + ch];                  // uniform -> s_load
        const float* __restrict__ src = prev_outputs + (size_t)p * (NSP * NSP);
        const float* wc = Wt + ((size_t)k * FAN_IN + ch) * 9;           // uniform -> s_load
        float w[9];
        #pragma unroll
        for (int i = 0; i < 9; ++i) w[i] = wc[i];

        #pragma unroll
        for (int j = 0; j < 6; ++j) {
            // input global row for this tap-row, clamped; mask kills clamped rows
            int gr = r0 - 1 + j;
            gr = (gr < 0) ? 0 : (gr > 63 ? 63 : gr);
            const float* rp = src + gr * NSP;

            float4 m  = *(const float4*)(rp + c0);   // 16B aligned (c0 % 4 == 0)
            float  l  = rp[cL] * mL;
            float  r_ = rp[cR] * mR;

            if (j == 0) { m.x *= mT; m.y *= mT; m.z *= mT; m.w *= mT; l *= mT; r_ *= mT; }
            if (j == 5) { m.x *= mB; m.y *= mB; m.z *= mB; m.w *= mB; l *= mB; r_ *= mB; }

            // input row j feeds output rows r in [j-2, j] ∩ [0,3], weight row = j - r
            const int rlo = (j >= 2) ? (j - 2) : 0;
            const int rhi = (j <= 3) ? j : 3;
            #pragma unroll
            for (int r = rlo; r <= rhi; ++r) {
                const float w0 = w[(j - r) * 3 + 0];
                const float w1 = w[(j - r) * 3 + 1];
                const float w2 = w[(j - r) * 3 + 2];
                acc[r][0] = fmaf(w0, l,   fmaf(w1, m.x, fmaf(w2, m.y, acc[r][0])));
                acc[r][1] = fmaf(w0, m.x, fmaf(w1, m.y, fmaf(w2, m.z, acc[r][1])));
                acc[r][2] = fmaf(w0, m.y, fmaf(w1, m.z, fmaf(w2, m.w, acc[r][2])));
                acc[r][3] = fmaf(w0, m.z, fmaf(w1, m.w, fmaf(w2, r_,  acc[r][3])));
            }
        }
    }

    const float bk = bias[k];
    #pragma unroll
    for (int r = 0; r < 4; ++r) {
        float4 o;
        o.x = tanh_fast(acc[r][0] + bk);
        o.y = tanh_fast(acc[r][1] + bk);
        o.z = tanh_fast(acc[r][2] + bk);
        o.w = tanh_fast(acc[r][3] + bk);
        *(float4*)(out + obase + (size_t)(r0 + r) * NSP + c0) = o;
    }
}

extern "C" void kernel_launch(void* const* d_in, const int* in_sizes, int n_in,
                              void* d_out, int out_size, void* d_ws, size_t ws_size,
                              hipStream_t stream) {
    const float* prev_outputs   = (const float*)d_in[0];
    const void*  prev_is_active = d_in[1];
    const int*   parent_indices = (const int*)d_in[2];
    const float* Wt             = (const float*)d_in[3];
    const float* bias           = (const float*)d_in[4];
    float*       out            = (float*)d_out;

    decoder_kernel<<<dim3(KN), dim3(256), 0, stream>>>(
        prev_outputs, prev_is_active, parent_indices, Wt, bias, out);
}

// Round 4
// 39.964 us; speedup vs baseline: 1.8307x; 1.8307x over previous
//
#include <hip/hip_runtime.h>

#define KN      1024
#define FAN_IN  16
#define NSP     64
#define THRESH  12

__device__ __forceinline__ float tanh_fast(float x) {
    float ax = fabsf(x);
    float e  = __expf(-2.0f * ax);
    float r  = 1.0f - 2.0f * e * __builtin_amdgcn_rcpf(1.0f + e);
    return copysignf(r, x);
}

__device__ __forceinline__ float bperm(int idx_bytes, float v) {
    return __int_as_float(__builtin_amdgcn_ds_bpermute(idx_bytes, __float_as_int(v)));
}

// Load 10 rows of this lane's column (rows r0-1 .. r0+8, clamped).
__device__ __forceinline__ void load_rows(const float* __restrict__ base, int r0, float v[10]) {
    #pragma unroll
    for (int j = 0; j < 10; ++j) {
        int gr = r0 - 1 + j;
        gr = (gr < 0) ? 0 : (gr > 63 ? 63 : gr);
        v[j] = base[gr * NSP];
    }
}

// 2 blocks per node, 256 threads = 4 waves. Wave owns 8 output rows; lane owns 1 col.
// Per channel: 10 coalesced scalar loads; L/R columns via ds_bpermute from neighbor lanes.
__global__ __launch_bounds__(256, 6) void decoder_kernel(
    const float* __restrict__ prev_outputs,      // [1024,64,64]
    const void*  __restrict__ prev_is_active,    // [1024] bool(1B) or int32 (sniffed)
    const int*   __restrict__ parent_indices,    // [1024,16]
    const float* __restrict__ Wt,                // [1024,16,3,3]
    const float* __restrict__ bias,              // [1024]
    float*       __restrict__ out)               // [1024*4096] + [1024] activity
{
    const int bid  = blockIdx.x;
    const int k    = bid >> 1;
    const int half = bid & 1;
    const int tid  = threadIdx.x;
    const int lane = tid & 63;                   // column
    const int wv   = tid >> 6;                   // wave id
    const int r0   = half * 32 + wv * 8;         // first of 8 output rows (uniform/wave)

    // --- sniff flag encoding: numpy bool (1 byte) vs int32. Deterministic. ---
    bool bytemode = false;
    {
        const unsigned* sv = (const unsigned*)prev_is_active;
        #pragma unroll
        for (int i = 0; i < 16; ++i)
            if (sv[i] > 1u) bytemode = true;
    }

    // --- activity gate (uniform) ---
    int cnt = 0;
    #pragma unroll
    for (int i = 0; i < FAN_IN; ++i) {
        int p = parent_indices[k * FAN_IN + i];
        int f;
        if (bytemode) f = (((const unsigned char*)prev_is_active)[p] != 0);
        else          f = (((const int*)prev_is_active)[p] != 0);
        cnt += f;
    }
    const bool active = (cnt >= THRESH);

    const size_t obase = (size_t)k * (NSP * NSP);
    if (half == 0 && tid == 0)
        out[(size_t)KN * NSP * NSP + k] = active ? 1.0f : 0.0f;

    if (!active) {
        float4 z = make_float4(0.f, 0.f, 0.f, 0.f);
        float4* o4 = (float4*)(out + obase + (size_t)half * 32 * NSP);
        #pragma unroll
        for (int i = tid; i < 32 * NSP / 4; i += 256) o4[i] = z;
        return;
    }

    const float mL = (lane > 0)  ? 1.0f : 0.0f;
    const float mR = (lane < 63) ? 1.0f : 0.0f;
    const float mT = (r0 > 0)    ? 1.0f : 0.0f;   // uniform
    const float mB = (r0 < 56)   ? 1.0f : 0.0f;   // uniform
    const int idxL = ((lane - 1) & 63) << 2;      // bpermute byte index
    const int idxR = ((lane + 1) & 63) << 2;

    float acc[8];
    #pragma unroll
    for (int s = 0; s < 8; ++s) acc[s] = 0.0f;

    const int* pidx = parent_indices + k * FAN_IN;
    const float* wbase = Wt + (size_t)k * FAN_IN * 9;

    // ---- channel compute: v[10] (top/bottom already masked), 9 weights ----
#define COMPUTE_CH(v, wc)                                                     \
    {                                                                         \
        const float wl0 = (wc)[0] * mL, wr0 = (wc)[2] * mR;                   \
        const float wl1 = (wc)[3] * mL, wr1 = (wc)[5] * mR;                   \
        const float wl2 = (wc)[6] * mL, wr2 = (wc)[8] * mR;                   \
        const float wc0 = (wc)[1], wc1 = (wc)[4], wc2 = (wc)[7];              \
        float la = bperm(idxL, (v)[0]), ra = bperm(idxR, (v)[0]);             \
        float lb = bperm(idxL, (v)[1]), rb = bperm(idxR, (v)[1]);             \
        _Pragma("unroll")                                                     \
        for (int s = 0; s < 8; ++s) {                                         \
            float lc_ = bperm(idxL, (v)[s + 2]);                              \
            float rc_ = bperm(idxR, (v)[s + 2]);                              \
            float a = acc[s];                                                 \
            a = fmaf(wl0, la, a); a = fmaf(wc0, (v)[s],     a); a = fmaf(wr0, ra, a); \
            a = fmaf(wl1, lb, a); a = fmaf(wc1, (v)[s + 1], a); a = fmaf(wr1, rb, a); \
            a = fmaf(wl2, lc_, a); a = fmaf(wc2, (v)[s + 2], a); a = fmaf(wr2, rc_, a); \
            acc[s] = a;                                                       \
            la = lb; ra = rb; lb = lc_; rb = rc_;                             \
        }                                                                     \
    }

    float vA[10], vB[10];
    float wA[9], wB[9];

    // prologue: channel 0 into A
    {
        const float* srcA = prev_outputs + (size_t)pidx[0] * (NSP * NSP) + lane;
        load_rows(srcA, r0, vA);
        #pragma unroll
        for (int i = 0; i < 9; ++i) wA[i] = wbase[0 * 9 + i];
    }

    #pragma unroll
    for (int ch = 0; ch < FAN_IN; ch += 2) {
        // issue loads for ch+1 into B, then compute A
        {
            const float* srcB = prev_outputs + (size_t)pidx[ch + 1] * (NSP * NSP) + lane;
            load_rows(srcB, r0, vB);
            #pragma unroll
            for (int i = 0; i < 9; ++i) wB[i] = wbase[(ch + 1) * 9 + i];
        }
        vA[0] *= mT; vA[9] *= mB;
        COMPUTE_CH(vA, wA);

        // issue loads for ch+2 into A (if any), then compute B
        if (ch + 2 < FAN_IN) {
            const float* srcA = prev_outputs + (size_t)pidx[ch + 2] * (NSP * NSP) + lane;
            load_rows(srcA, r0, vA);
            #pragma unroll
            for (int i = 0; i < 9; ++i) wA[i] = wbase[(ch + 2) * 9 + i];
        }
        vB[0] *= mT; vB[9] *= mB;
        COMPUTE_CH(vB, wB);
    }
#undef COMPUTE_CH

    const float bk = bias[k];
    #pragma unroll
    for (int s = 0; s < 8; ++s) {
        out[obase + (size_t)(r0 + s) * NSP + lane] = tanh_fast(acc[s] + bk);
    }
}

extern "C" void kernel_launch(void* const* d_in, const int* in_sizes, int n_in,
                              void* d_out, int out_size, void* d_ws, size_t ws_size,
                              hipStream_t stream) {
    const float* prev_outputs   = (const float*)d_in[0];
    const void*  prev_is_active = d_in[1];
    const int*   parent_indices = (const int*)d_in[2];
    const float* Wt             = (const float*)d_in[3];
    const float* bias           = (const float*)d_in[4];
    float*       out            = (float*)d_out;

    decoder_kernel<<<dim3(KN * 2), dim3(256), 0, stream>>>(
        prev_outputs, prev_is_active, parent_indices, Wt, bias, out);
}

// Round 9
// 39.494 us; speedup vs baseline: 1.8524x; 1.0119x over previous
//
#include <hip/hip_runtime.h>

#define KN      1024
#define FAN_IN  16
#define NSP     64
#define THRESH  12

__device__ __forceinline__ float tanh_fast(float x) {
    float ax = fabsf(x);
    float e  = __expf(-2.0f * ax);
    float r  = 1.0f - 2.0f * e * __builtin_amdgcn_rcpf(1.0f + e);
    return copysignf(r, x);
}

// DPP lane shifts within 16-lane rows (aligned with cg groups). bound_ctrl=1
// zeroes the shifted-in lane at row edges — exactly the conv zero-pad columns.
__device__ __forceinline__ float dpp_shr1(float x) {  // lane L <- lane L-1
    return __int_as_float(__builtin_amdgcn_update_dpp(
        0, __float_as_int(x), 0x111, 0xF, 0xF, true));
}
__device__ __forceinline__ float dpp_shl1(float x) {  // lane L <- lane L+1
    return __int_as_float(__builtin_amdgcn_update_dpp(
        0, __float_as_int(x), 0x101, 0xF, 0xF, true));
}

// Frame: 2 blocks/node, 256 threads (4 waves), k = bid>>1 (R3-proven).
// Core: thread owns a 2x4 output tile; rp = half*16 + (tid>>4) in 0..31,
// rows 2*rp, 2*rp+1; cols 4*cg..4*cg+3. Per channel: 4 global float4 loads
// (rows rA-1..rA+2, clamped + value-masked), halo cols via DPP. No LDS.
// BOUNDARY FIX vs R4-R7: weights are NEVER masked; only the halo VALUES
// l (x[c0-1]) and r (x[c0+4]) are masked — they are the only OOB elements.
__global__ __launch_bounds__(256) void decoder_kernel(
    const float* __restrict__ prev_outputs,      // [1024,64,64]
    const void*  __restrict__ prev_is_active,    // [1024] bool(1B) or int32 (sniffed)
    const int*   __restrict__ parent_indices,    // [1024,16]
    const float* __restrict__ Wt,                // [1024,16,3,3]
    const float* __restrict__ bias,              // [1024]
    float*       __restrict__ out)               // [1024*4096] + [1024] activity
{
    const int bid  = blockIdx.x;
    const int k    = bid >> 1;
    const int half = bid & 1;
    const int tid  = threadIdx.x;
    const int cg   = tid & 15;
    const int rp   = half * 16 + (tid >> 4);     // 0..31
    const int c0   = cg * 4;
    const int rA   = 2 * rp;                     // output rows rA, rA+1

    // --- sniff flag encoding: numpy bool (1 byte) vs int32. Deterministic. ---
    bool bytemode = false;
    {
        const unsigned* sv = (const unsigned*)prev_is_active;
        #pragma unroll
        for (int i = 0; i < 16; ++i)
            if (sv[i] > 1u) bytemode = true;
    }

    // --- activity gate (uniform scalar work) ---
    const int* pidx = parent_indices + k * FAN_IN;
    int cnt = 0;
    #pragma unroll
    for (int i = 0; i < FAN_IN; ++i) {
        int p = pidx[i];
        int f;
        if (bytemode) f = (((const unsigned char*)prev_is_active)[p] != 0);
        else          f = (((const int*)prev_is_active)[p] != 0);
        cnt += f;
    }
    const bool active = (cnt >= THRESH);

    const size_t obase = (size_t)k * (NSP * NSP);
    if (half == 0 && tid == 0)
        out[(size_t)KN * NSP * NSP + k] = active ? 1.0f : 0.0f;

    if (!active) {
        float4 z = make_float4(0.f, 0.f, 0.f, 0.f);
        float4* o4 = (float4*)(out + obase + (size_t)half * 32 * NSP);
        o4[tid]       = z;
        o4[tid + 256] = z;
        return;
    }

    // boundary machinery: row masks (whole OOB rows), halo-value masks (OOB cols)
    const float mL = (cg > 0)  ? 1.0f : 0.0f;    // x[c0-1] valid?
    const float mR = (cg < 15) ? 1.0f : 0.0f;    // x[c0+4] valid?
    const float mT = (rp > 0)  ? 1.0f : 0.0f;
    const float mB = (rp < 31) ? 1.0f : 0.0f;
    const int   gr0 = (rp > 0)  ? rA - 1 : 0;    // clamped input rows (value-masked)
    const int   gr3 = (rp < 31) ? rA + 2 : 63;

    const float* wbase = Wt + (size_t)k * FAN_IN * 9;

    float acc[8];
    #pragma unroll
    for (int s = 0; s < 8; ++s) acc[s] = 0.0f;

#define ROW_FMA(base, W0, W1, W2)                                              \
    acc[(base)+0] = fmaf(W0, l,   fmaf(W1, m.x, fmaf(W2, m.y, acc[(base)+0])));\
    acc[(base)+1] = fmaf(W0, m.x, fmaf(W1, m.y, fmaf(W2, m.z, acc[(base)+1])));\
    acc[(base)+2] = fmaf(W0, m.y, fmaf(W1, m.z, fmaf(W2, m.w, acc[(base)+2])));\
    acc[(base)+3] = fmaf(W0, m.z, fmaf(W1, m.w, fmaf(W2, r,   acc[(base)+3])));

    for (int ch = 0; ch < FAN_IN; ++ch) {
        const int p = pidx[ch];                                // uniform -> s_load
        const float* __restrict__ src = prev_outputs + (size_t)p * (NSP * NSP);

        // 4 independent wide loads up front (memory-level parallelism in-wave)
        const float4 v0 = *(const float4*)(src + gr0      * NSP + c0);
        const float4 v1 = *(const float4*)(src + rA       * NSP + c0);
        const float4 v2 = *(const float4*)(src + (rA + 1) * NSP + c0);
        const float4 v3 = *(const float4*)(src + gr3      * NSP + c0);

        const float* w = wbase + ch * 9;                       // uniform -> s_loads
        const float wl0 = w[0], wc0 = w[1], wr0 = w[2];        // UNMASKED weights
        const float wl1 = w[3], wc1 = w[4], wr1 = w[5];
        const float wl2 = w[6], wc2 = w[7], wr2 = w[8];

        float4 m; float l, r;

        // j=0: input row rA-1 (mT-masked) -> out row rA, weight row 0
        m = v0; l = dpp_shr1(m.w) * mL; r = dpp_shl1(m.x) * mR;
        m.x *= mT; m.y *= mT; m.z *= mT; m.w *= mT; l *= mT; r *= mT;
        ROW_FMA(0, wl0, wc0, wr0);

        // j=1: input row rA -> out rA (wrow 1), out rA+1 (wrow 0)
        m = v1; l = dpp_shr1(m.w) * mL; r = dpp_shl1(m.x) * mR;
        ROW_FMA(0, wl1, wc1, wr1);
        ROW_FMA(4, wl0, wc0, wr0);

        // j=2: input row rA+1 -> out rA (wrow 2), out rA+1 (wrow 1)
        m = v2; l = dpp_shr1(m.w) * mL; r = dpp_shl1(m.x) * mR;
        ROW_FMA(0, wl2, wc2, wr2);
        ROW_FMA(4, wl1, wc1, wr1);

        // j=3: input row rA+2 (mB-masked) -> out rA+1, weight row 2
        m = v3; l = dpp_shr1(m.w) * mL; r = dpp_shl1(m.x) * mR;
        m.x *= mB; m.y *= mB; m.z *= mB; m.w *= mB; l *= mB; r *= mB;
        ROW_FMA(4, wl2, wc2, wr2);
    }
#undef ROW_FMA

    const float bk = bias[k];
    float4 o0, o1;
    o0.x = tanh_fast(acc[0] + bk); o0.y = tanh_fast(acc[1] + bk);
    o0.z = tanh_fast(acc[2] + bk); o0.w = tanh_fast(acc[3] + bk);
    o1.x = tanh_fast(acc[4] + bk); o1.y = tanh_fast(acc[5] + bk);
    o1.z = tanh_fast(acc[6] + bk); o1.w = tanh_fast(acc[7] + bk);
    *(float4*)(out + obase + (size_t)rA       * NSP + c0) = o0;
    *(float4*)(out + obase + (size_t)(rA + 1) * NSP + c0) = o1;
}

extern "C" void kernel_launch(void* const* d_in, const int* in_sizes, int n_in,
                              void* d_out, int out_size, void* d_ws, size_t ws_size,
                              hipStream_t stream) {
    const float* prev_outputs   = (const float*)d_in[0];
    const void*  prev_is_active = d_in[1];
    const int*   parent_indices = (const int*)d_in[2];
    const float* Wt             = (const float*)d_in[3];
    const float* bias           = (const float*)d_in[4];
    float*       out            = (float*)d_out;

    decoder_kernel<<<dim3(KN * 2), dim3(256), 0, stream>>>(
        prev_outputs, prev_is_active, parent_indices, Wt, bias, out);
}

// Round 10
// 39.101 us; speedup vs baseline: 1.8711x; 1.0101x over previous
//
#include <hip/hip_runtime.h>

#define KN      1024
#define FAN_IN  16
#define NSP     64
#define THRESH  12

__device__ __forceinline__ float tanh_fast(float x) {
    float ax = fabsf(x);
    float e  = __expf(-2.0f * ax);
    float r  = 1.0f - 2.0f * e * __builtin_amdgcn_rcpf(1.0f + e);
    return copysignf(r, x);
}

// Full-wave DPP shifts (gfx9 wave_shr1/wave_shl1). bound_ctrl=1 zeroes the
// shifted-in edge lane — exactly the conv zero-pad at col 0 / col 63.
__device__ __forceinline__ float dpp_wshr1(float x) {  // lane L <- lane L-1
    return __int_as_float(__builtin_amdgcn_update_dpp(
        0, __float_as_int(x), 0x138, 0xF, 0xF, true));
}
__device__ __forceinline__ float dpp_wshl1(float x) {  // lane L <- lane L+1
    return __int_as_float(__builtin_amdgcn_update_dpp(
        0, __float_as_int(x), 0x130, 0xF, 0xF, true));
}

// async global->LDS DMA, 16 B per lane. LDS base is wave-uniform; HW writes
// base + lane*16. Global src is per-lane (guide m104/m108 semantics).
__device__ __forceinline__ void gload_lds16(const float* g, float* l) {
    __builtin_amdgcn_global_load_lds(
        (const __attribute__((address_space(1))) unsigned*)g,
        (__attribute__((address_space(3)))       unsigned*)l,
        16, 0, 0);
}

// 1 block = 1 node, 512 threads (8 waves). Wave wv owns output rows 8wv..8wv+7;
// lane = column. Per channel: full 16 KB map DMA'd to LDS (double-buffered,
// one barrier per channel); compute = 10 ds_read_b32 rows + DPP halo cols +
// 72 FMAs. Boundary fix from R8 retained: only OOB VALUES are masked.
__global__ __launch_bounds__(512, 8) void decoder_kernel(
    const float* __restrict__ prev_outputs,      // [1024,64,64]
    const void*  __restrict__ prev_is_active,    // [1024] bool(1B) or int32 (sniffed)
    const int*   __restrict__ parent_indices,    // [1024,16]
    const float* __restrict__ Wt,                // [1024,16,3,3]
    const float* __restrict__ bias,              // [1024]
    float*       __restrict__ out)               // [1024*4096] + [1024] activity
{
    __shared__ float sbuf[2][NSP * NSP];         // 2 x 16 KB

    const int k    = blockIdx.x;
    const int tid  = threadIdx.x;
    const int lane = tid & 63;                   // column
    const int wv   = tid >> 6;                   // wave id, uniform
    const int r0   = wv * 8;                     // first of 8 output rows

    // --- sniff flag encoding: numpy bool (1 byte) vs int32. Deterministic. ---
    bool bytemode = false;
    {
        const unsigned* sv = (const unsigned*)prev_is_active;
        #pragma unroll
        for (int i = 0; i < 16; ++i)
            if (sv[i] > 1u) bytemode = true;
    }

    // --- activity gate (uniform scalar work) ---
    const int* pidx = parent_indices + k * FAN_IN;
    int cnt = 0;
    #pragma unroll
    for (int i = 0; i < FAN_IN; ++i) {
        int p = pidx[i];
        int f;
        if (bytemode) f = (((const unsigned char*)prev_is_active)[p] != 0);
        else          f = (((const int*)prev_is_active)[p] != 0);
        cnt += f;
    }
    const bool active = (cnt >= THRESH);

    const size_t obase = (size_t)k * (NSP * NSP);
    if (tid == 0)
        out[(size_t)KN * NSP * NSP + k] = active ? 1.0f : 0.0f;

    if (!active) {                   // uniform early-exit: no barriers executed
        float4 z = make_float4(0.f, 0.f, 0.f, 0.f);
        float4* o4 = (float4*)(out + obase);
        o4[tid]       = z;
        o4[tid + 512] = z;
        return;
    }

    // uniform row-boundary machinery (cols handled by DPP bound_ctrl)
    const float mT = (wv > 0) ? 1.0f : 0.0f;     // row r0-1 valid?
    const float mB = (wv < 7) ? 1.0f : 0.0f;     // row r0+8 valid?
    const int   rT = (wv > 0) ? r0 - 1 : 0;      // clamped (value-masked)
    const int   rB = (wv < 7) ? r0 + 8 : 63;

    const float* wbase = Wt + (size_t)k * FAN_IN * 9;

    float acc[8];
    #pragma unroll
    for (int s = 0; s < 8; ++s) acc[s] = 0.0f;

    // stage one 16 KB map into sbuf[buf]: 2 rounds of 512 lanes x 16 B.
    // LDS base per call is wave-uniform (wv*256 floats); HW adds lane*16 B.
#define STAGE(buf, p)                                                         \
    {                                                                         \
        const float* g = prev_outputs + (size_t)(p) * (NSP * NSP);            \
        gload_lds16(g + tid * 4,        &sbuf[buf][wv * 256]);                \
        gload_lds16(g + 2048 + tid * 4, &sbuf[buf][2048 + wv * 256]);         \
    }

    STAGE(0, pidx[0]);
    __syncthreads();                 // vmcnt(0) drain + handoff: buf0 ready

    #pragma unroll 2
    for (int ch = 0; ch < FAN_IN; ++ch) {
        if (ch + 1 < FAN_IN) STAGE((ch + 1) & 1, pidx[ch + 1]);

        const float* sb = sbuf[ch & 1];
        const float* w  = wbase + ch * 9;        // uniform -> s_loads
        const float wl0 = w[0], wc0 = w[1], wr0 = w[2];
        const float wl1 = w[3], wc1 = w[4], wr1 = w[5];
        const float wl2 = w[6], wc2 = w[7], wr2 = w[8];

        // v[j] = input row r0-1+j (j=0..9), this lane's column
        float v[10], l[10], r[10];
        v[0] = sb[rT * NSP + lane] * mT;
        #pragma unroll
        for (int j = 1; j <= 8; ++j) v[j] = sb[(r0 - 1 + j) * NSP + lane];
        v[9] = sb[rB * NSP + lane] * mB;
        #pragma unroll
        for (int j = 0; j < 10; ++j) { l[j] = dpp_wshr1(v[j]); r[j] = dpp_wshl1(v[j]); }

        // out row r0+s uses input rows v[s],v[s+1],v[s+2] with weight rows 0,1,2
        #pragma unroll
        for (int s = 0; s < 8; ++s) {
            float a = acc[s];
            a = fmaf(wl0, l[s],     fmaf(wc0, v[s],     fmaf(wr0, r[s],     a)));
            a = fmaf(wl1, l[s + 1], fmaf(wc1, v[s + 1], fmaf(wr1, r[s + 1], a)));
            a = fmaf(wl2, l[s + 2], fmaf(wc2, v[s + 2], fmaf(wr2, r[s + 2], a)));
            acc[s] = a;
        }

        if (ch + 1 < FAN_IN) __syncthreads();    // drain DMA + buffer handoff
    }
#undef STAGE

    const float bk = bias[k];
    #pragma unroll
    for (int s = 0; s < 8; ++s)
        out[obase + (size_t)(r0 + s) * NSP + lane] = tanh_fast(acc[s] + bk);
}

extern "C" void kernel_launch(void* const* d_in, const int* in_sizes, int n_in,
                              void* d_out, int out_size, void* d_ws, size_t ws_size,
                              hipStream_t stream) {
    const float* prev_outputs   = (const float*)d_in[0];
    const void*  prev_is_active = d_in[1];
    const int*   parent_indices = (const int*)d_in[2];
    const float* Wt             = (const float*)d_in[3];
    const float* bias           = (const float*)d_in[4];
    float*       out            = (float*)d_out;

    decoder_kernel<<<dim3(KN), dim3(512), 0, stream>>>(
        prev_outputs, prev_is_active, parent_indices, Wt, bias, out);
}